// Round 1
// baseline (170.077 us; speedup 1.0000x reference)
//
#include <hip/hip_runtime.h>
#include <stdint.h>

typedef short bf16x8 __attribute__((ext_vector_type(8)));
typedef float f32x4 __attribute__((ext_vector_type(4)));
typedef unsigned short u16;

#define MFMA16(a, b, c) __builtin_amdgcn_mfma_f32_16x16x32_bf16((a), (b), (c), 0, 0, 0)

static __device__ __forceinline__ u16 f2bf(float f) {
  union { float f; uint32_t u; } v; v.f = f;
  uint32_t u = v.u;
  u += 0x7FFFu + ((u >> 16) & 1u);   // RNE
  return (u16)(u >> 16);
}
static __device__ __forceinline__ uint32_t pk2bf(float a, float b) {
  return (uint32_t)f2bf(a) | ((uint32_t)f2bf(b) << 16);
}

// ---------------- kernel 0: W -> W^T bf16 [192][1024], Wq rows scaled by 1/8 ----
__global__ __launch_bounds__(256) void prep_wt(const float* __restrict__ Wk,
                                               const float* __restrict__ Wq,
                                               const float* __restrict__ Wv,
                                               u16* __restrict__ WT) {
  int idx = blockIdx.x * 256 + threadIdx.x;
  if (idx >= 192 * 1024) return;
  int n = idx >> 10, k = idx & 1023;
  float v;
  if (n < 64)        v = Wq[k * 64 + n] * 0.125f;     // fold 1/sqrt(64) into Q
  else if (n < 128)  v = Wk[k * 64 + (n - 64)];
  else               v = Wv[k * 64 + (n - 128)];
  WT[idx] = f2bf(v);
}

// ---------------- kernel 1: QKV projection (bf16 MFMA GEMM) --------------------
// out: Q [b][s][64] bf16 (pre-scaled), K [b][s][64] bf16, VT [b][64][4096] bf16
__global__ __launch_bounds__(128) void qkv_proj(const float* __restrict__ x,
                                                const u16* __restrict__ WT,
                                                u16* __restrict__ Q,
                                                u16* __restrict__ K,
                                                u16* __restrict__ VT) {
  const int lane = threadIdx.x & 63;
  const int wv   = threadIdx.x >> 6;   // 0..1
  const int l15  = lane & 15, g = lane >> 4;
  const long r0 = (long)blockIdx.x * 64 + wv * 32;   // 32 rows per wave

  f32x4 acc[2][12];
#pragma unroll
  for (int rb = 0; rb < 2; ++rb)
#pragma unroll
    for (int n = 0; n < 12; ++n) acc[rb][n] = (f32x4){0.f, 0.f, 0.f, 0.f};

  for (int k0 = 0; k0 < 1024; k0 += 32) {
    bf16x8 a[2];
#pragma unroll
    for (int rb = 0; rb < 2; ++rb) {
      const float* ap = x + (r0 + rb * 16 + l15) * 1024 + k0 + 8 * g;
      float4 f0 = *(const float4*)ap;
      float4 f1 = *(const float4*)(ap + 4);
      union { uint32_t u[4]; bf16x8 v; } cv;
      cv.u[0] = pk2bf(f0.x, f0.y);
      cv.u[1] = pk2bf(f0.z, f0.w);
      cv.u[2] = pk2bf(f1.x, f1.y);
      cv.u[3] = pk2bf(f1.z, f1.w);
      a[rb] = cv.v;
    }
#pragma unroll
    for (int n = 0; n < 12; ++n) {
      bf16x8 bf = *(const bf16x8*)(WT + (n * 16 + l15) * 1024 + k0 + 8 * g);
      acc[0][n] = MFMA16(a[0], bf, acc[0][n]);
      acc[1][n] = MFMA16(a[1], bf, acc[1][n]);
    }
  }

#pragma unroll
  for (int rb = 0; rb < 2; ++rb) {
    const long s = r0 + rb * 16;
    // Q (ntiles 0..3) and K (ntiles 4..7): row = 4g+i, col = 16n+l15
#pragma unroll
    for (int n = 0; n < 4; ++n)
#pragma unroll
      for (int i = 0; i < 4; ++i) {
        Q[(s + 4 * g + i) * 64 + n * 16 + l15] = f2bf(acc[rb][n][i]);
        K[(s + 4 * g + i) * 64 + n * 16 + l15] = f2bf(acc[rb][n + 4][i]);
      }
    // V transposed: VT[b][h][s]; lane's 4 rows are consecutive s -> 8B packed store
    const int b = (int)(s >> 12), sb = (int)(s & 4095);
#pragma unroll
    for (int n = 0; n < 4; ++n) {
      uint2 val;
      val.x = pk2bf(acc[rb][n + 8][0], acc[rb][n + 8][1]);
      val.y = pk2bf(acc[rb][n + 8][2], acc[rb][n + 8][3]);
      *(uint2*)(VT + (long)b * 64 * 4096 + (n * 16 + l15) * 4096 + sb + 4 * g) = val;
    }
  }
}

// ---------------- kernel 2: flash attention ------------------------------------
// grid: b * 64 qtiles; block: 4 waves, each wave owns 16 q rows.
// Swapped QK^T: st = mfma(A=K, B=Q) -> lane holds S^T[k=16tt+4g+i][q=l15].
// P staged per-wave in XOR-swizzled LDS to reach MFMA-A layout for PV.
__global__ __launch_bounds__(256) void flash_attn(const u16* __restrict__ Q,
                                                  const u16* __restrict__ K,
                                                  const u16* __restrict__ VT,
                                                  float* __restrict__ out) {
  __shared__ char plds[4 * 2048];   // per wave: 16 rows x 128 B
  const int lane = threadIdx.x & 63, wv = threadIdx.x >> 6;
  const int l15 = lane & 15, g = lane >> 4;
  const int b = blockIdx.x >> 6, qt = blockIdx.x & 63;
  const long qbase = (long)b * 4096 + qt * 64 + wv * 16;
  char* P = plds + wv * 2048;

  bf16x8 qf[2];
#pragma unroll
  for (int c = 0; c < 2; ++c)
    qf[c] = *(const bf16x8*)(Q + (qbase + l15) * 64 + 32 * c + 8 * g);

  f32x4 o[4];
#pragma unroll
  for (int n = 0; n < 4; ++n) o[n] = (f32x4){0.f, 0.f, 0.f, 0.f};
  float m = -1e30f, lsum = 0.f;

  const u16* Kb = K + (long)b * 4096 * 64;
  const u16* Vb = VT + (long)b * 64 * 4096;

  // prefetch K tile 0
  bf16x8 kf[4][2];
#pragma unroll
  for (int tt = 0; tt < 4; ++tt)
#pragma unroll
    for (int c = 0; c < 2; ++c)
      kf[tt][c] = *(const bf16x8*)(Kb + (tt * 16 + l15) * 64 + 32 * c + 8 * g);

  for (int t = 0; t < 64; ++t) {
    // issue V^T fragment loads early (consumed at the end of the iteration)
    bf16x8 vf[4][2];
#pragma unroll
    for (int n = 0; n < 4; ++n)
#pragma unroll
      for (int c = 0; c < 2; ++c)
        vf[n][c] = *(const bf16x8*)(Vb + (n * 16 + l15) * 4096 + t * 64 + 32 * c + 8 * g);

    // S^T = K_tile . Q^T  (contraction over h=64 in two 32-chunks)
    f32x4 st[4];
#pragma unroll
    for (int tt = 0; tt < 4; ++tt) st[tt] = (f32x4){0.f, 0.f, 0.f, 0.f};
#pragma unroll
    for (int tt = 0; tt < 4; ++tt)
#pragma unroll
      for (int c = 0; c < 2; ++c)
        st[tt] = MFMA16(kf[tt][c], qf[c], st[tt]);

    // prefetch next K tile during softmax
    if (t < 63) {
#pragma unroll
      for (int tt = 0; tt < 4; ++tt)
#pragma unroll
        for (int c = 0; c < 2; ++c)
          kf[tt][c] = *(const bf16x8*)(Kb + ((t + 1) * 64 + tt * 16 + l15) * 64 + 32 * c + 8 * g);
    }

    // ---- online softmax (per q = l15; 4 g-groups hold replicas) ----
    f32x4 vm = st[0];
#pragma unroll
    for (int tt = 1; tt < 4; ++tt)
#pragma unroll
      for (int i = 0; i < 4; ++i) vm[i] = fmaxf(vm[i], st[tt][i]);
    float tmax = fmaxf(fmaxf(vm[0], vm[1]), fmaxf(vm[2], vm[3]));
    tmax = fmaxf(tmax, __shfl_xor(tmax, 16));
    tmax = fmaxf(tmax, __shfl_xor(tmax, 32));
    float mnew = fmaxf(m, tmax);
    float corr = __expf(m - mnew);
    float rsum = 0.f;
#pragma unroll
    for (int tt = 0; tt < 4; ++tt)
#pragma unroll
      for (int i = 0; i < 4; ++i) {
        float p = __expf(st[tt][i] - mnew);
        st[tt][i] = p;
        rsum += p;
      }
    rsum += __shfl_xor(rsum, 16);
    rsum += __shfl_xor(rsum, 32);
    lsum = lsum * corr + rsum;
    m = mnew;

    // ---- P -> LDS (row q=l15, k=16tt+4g..+3), XOR-swizzled, 8B stores ----
#pragma unroll
    for (int tt = 0; tt < 4; ++tt) {
      uint2 val;
      val.x = pk2bf(st[tt][0], st[tt][1]);
      val.y = pk2bf(st[tt][2], st[tt][3]);
      int off = l15 * 128 + tt * 32 + g * 8;
      off ^= (l15 & 7) << 4;
      *(uint2*)(P + off) = val;
    }

    // rescale O by corr (O rows are q = 4g+i in D-layout)
    float cd[4];
#pragma unroll
    for (int i = 0; i < 4; ++i) cd[i] = __shfl(corr, 4 * g + i);
#pragma unroll
    for (int n = 0; n < 4; ++n)
#pragma unroll
      for (int i = 0; i < 4; ++i) o[n][i] *= cd[i];

    // read P back as MFMA-A fragments (row q=l15, kk=32c+8g..+7)
    bf16x8 pa[2];
#pragma unroll
    for (int c = 0; c < 2; ++c) {
      int off = l15 * 128 + c * 64 + g * 16;
      off ^= (l15 & 7) << 4;
      pa[c] = *(const bf16x8*)(P + off);
    }

    // O += P . V  (contraction over k=64 in two 32-chunks, 4 h-tiles)
#pragma unroll
    for (int n = 0; n < 4; ++n)
#pragma unroll
      for (int c = 0; c < 2; ++c)
        o[n] = MFMA16(pa[c], vf[n][c], o[n]);
  }

  float linv = 1.f / lsum;
  float ld[4];
#pragma unroll
  for (int i = 0; i < 4; ++i) ld[i] = __shfl(linv, 4 * g + i);
#pragma unroll
  for (int n = 0; n < 4; ++n)
#pragma unroll
    for (int i = 0; i < 4; ++i)
      out[(qbase + 4 * g + i) * 64 + n * 16 + l15] = o[n][i] * ld[i];
}

// ---------------- launch --------------------------------------------------------
extern "C" void kernel_launch(void* const* d_in, const int* in_sizes, int n_in,
                              void* d_out, int out_size, void* d_ws, size_t ws_size,
                              hipStream_t stream) {
  const float* x  = (const float*)d_in[0];
  const float* Wk = (const float*)d_in[1];
  const float* Wq = (const float*)d_in[2];
  const float* Wv = (const float*)d_in[3];
  float* out = (float*)d_out;

  char* ws = (char*)d_ws;
  u16* WT = (u16*)ws;                                  // 192*1024*2   = 384 KiB
  u16* Q  = (u16*)(ws + 393216);                       // 16384*64*2   = 2 MiB
  u16* K  = (u16*)(ws + 393216 + 2097152);             // 2 MiB
  u16* VT = (u16*)(ws + 393216 + 2 * 2097152);         // 2 MiB

  prep_wt<<<768, 256, 0, stream>>>(Wk, Wq, Wv, WT);
  qkv_proj<<<256, 128, 0, stream>>>(x, WT, Q, K, VT);
  flash_attn<<<256, 256, 0, stream>>>(Q, K, VT, out);
}